// Round 15
// baseline (143.073 us; speedup 1.0000x reference)
//
#include <hip/hip_runtime.h>
#include <stdint.h>

#define BI 128
#define BT 128
#define RR 36
#define WW 50
#define DD 1024
#define NN 6400       /* fg row stride, static */
#define SEPS 1e-6f
#define L2E20 28.853900817779268f   /* 20/ln2 */

typedef __attribute__((ext_vector_type(8))) short short8v;
typedef __attribute__((ext_vector_type(4))) float float4v;
typedef __attribute__((ext_vector_type(2))) unsigned int uint2v;

__device__ __forceinline__ unsigned short f2bf(float f){
  unsigned u = __float_as_uint(f);
  return (unsigned short)((u + 0x7FFFu + ((u >> 16) & 1u)) >> 16);
}

// ---- prefix scans of il/cl + caption bucketing by clen>32 ----
__global__ __launch_bounds__(256) void prefix_kernel(
    const int* __restrict__ il, const int* __restrict__ cl,
    int* __restrict__ rowoff, int* __restrict__ coloff,
    int* __restrict__ cnts, int* __restrict__ listA, int* __restrict__ listB){
  __shared__ int buf[2][128];
  const int t = threadIdx.x;
  const int which = t >> 7, j = t & 127;
  const int v = which ? cl[j] : il[j];
  buf[which][j] = v;
  __syncthreads();
  #pragma unroll
  for (int off = 1; off < 128; off <<= 1){
    int x = (j >= off) ? buf[which][j - off] : 0;
    __syncthreads();
    buf[which][j] += x;
    __syncthreads();
  }
  int* dst = which ? coloff : rowoff;
  dst[j] = buf[which][j] - v;                 // exclusive
  if (j == 127) dst[128] = buf[which][127];   // total (M' / N')

  // ---- bucket captions: listA = {c: cl<=32} (2-slot), listB = {c: cl>32} ----
  __syncthreads();
  if (t < 128) buf[0][t] = (cl[t] > 32) ? 1 : 0;
  __syncthreads();
  #pragma unroll
  for (int off = 1; off < 128; off <<= 1){
    int x = (t >= off && t < 128) ? buf[0][t - off] : 0;
    __syncthreads();
    if (t < 128) buf[0][t] += x;
    __syncthreads();
  }
  if (t < 128){
    const int incl = buf[0][t];                // inclusive count of flagged
    if (cl[t] > 32) listB[incl - 1] = t;       // stable compaction
    else            listA[t - incl] = t;
    if (t == 127){ cnts[1] = incl; cnts[0] = 128 - incl; }
  }
}

// ---- gather valid rows + f32->bf16 convert. Block = one source row. ----
__global__ __launch_bounds__(256) void gather_cvt_kernel(
    const float* __restrict__ imgs, const float* __restrict__ caps,
    const int* __restrict__ il, const int* __restrict__ cl,
    const int* __restrict__ rowoff, const int* __restrict__ coloff,
    unsigned short* __restrict__ Ab, unsigned short* __restrict__ Bb){
  const int b = blockIdx.x;
  const int t = threadIdx.x;
  if (b < BI * RR){
    const int i = b / RR, r = b % RR;
    if (r >= il[i]) return;
    const float4 v = *(const float4*)(imgs + (size_t)b * DD + t * 4);
    ushort4 o = make_ushort4(f2bf(v.x), f2bf(v.y), f2bf(v.z), f2bf(v.w));
    *(ushort4*)(Ab + (size_t)(rowoff[i] + r) * DD + t * 4) = o;
  } else {
    const int bb = b - BI * RR;
    const int c = bb / WW, w = bb % WW;
    if (w >= cl[c]) return;
    const float4 v = *(const float4*)(caps + (size_t)bb * DD + t * 4);
    ushort4 o = make_ushort4(f2bf(v.x), f2bf(v.y), f2bf(v.z), f2bf(v.w));
    *(ushort4*)(Bb + (size_t)(coloff[c] + w) * DD + t * 4) = o;
  }
}

// ---- 128x128 GEMM, BK=32, triple-buffered LDS, depth-2 prefetch, compact
// grid + non-temporal C stores (validated R11-R14). ----
__global__ __launch_bounds__(256) void gemm_kernel(
    const unsigned short* __restrict__ A, const unsigned short* __restrict__ B,
    const int* __restrict__ rowoff, const int* __restrict__ coloff,
    float* __restrict__ C){
  __shared__ __align__(16) unsigned char LDS[49152];
  const int Mp = rowoff[BI];                      // M' (runtime)
  const int Np = coloff[BT];                      // N'
  const int nnb = (Np + 127) >> 7;
  const int nact = ((Mp + 127) >> 7) * nnb;
  const int bx = blockIdx.x;
  if (bx >= nact) return;                         // compact early-exit
  const int mb = bx / nnb, nb = bx - mb * nnb;
  const int m0 = mb * 128, n0 = nb * 128;

  const int tid = threadIdx.x;
  const int lane = tid & 63, wv = tid >> 6;
  const int l15 = lane & 15, lhi = lane >> 4;
  const int wr = wv >> 1, wc = wv & 1;            // 2x2 wave grid, 64x64/wave

  const unsigned short* sp[4];
  #pragma unroll
  for (int j = 0; j < 4; j++){
    const int u = j * 256 + tid;
    const int v = u & 511;
    const int sup = v >> 3, slot = v & 7;
    const int sub = slot ^ (sup & 7);             // inverse of store swizzle
    const int row = sup * 2 + (sub >> 2);
    const int kg  = sub & 3;
    sp[j] = ((u < 512) ? (A + (size_t)(m0 + row) * DD)
                       : (B + (size_t)(n0 + row) * DD)) + kg * 8;
  }

  float4v acc[4][4];
  #pragma unroll
  for (int a1 = 0; a1 < 4; a1++)
    #pragma unroll
    for (int b1 = 0; b1 < 4; b1++)
      acc[a1][b1] = (float4v){0.f, 0.f, 0.f, 0.f};

#define STAGE(BUF, CH) { \
    _Pragma("unroll") \
    for (int j = 0; j < 4; j++) \
      __builtin_amdgcn_global_load_lds( \
          (const __attribute__((address_space(1))) void*)(sp[j] + (CH) * 32), \
          (__attribute__((address_space(3))) void*)(LDS + (BUF) * 16384 + (j * 256 + tid) * 16), \
          16, 0, 0); }

#define LUNIT(row) (((row) >> 1) * 8 + (((((row) & 1) << 2) + lhi) ^ (((row) >> 1) & 7)))

#define COMPUTE(BUF) { \
    short8v af[4], bf[4]; \
    _Pragma("unroll") \
    for (int tr = 0; tr < 4; tr++){ \
      const int row = wr * 64 + tr * 16 + l15; \
      af[tr] = *(const short8v*)(LDS + (BUF) * 16384 + LUNIT(row) * 16); \
    } \
    _Pragma("unroll") \
    for (int tw = 0; tw < 4; tw++){ \
      const int row = wc * 64 + tw * 16 + l15; \
      bf[tw] = *(const short8v*)(LDS + (BUF) * 16384 + 8192 + LUNIT(row) * 16); \
    } \
    _Pragma("unroll") \
    for (int tr = 0; tr < 4; tr++) \
      _Pragma("unroll") \
      for (int tw = 0; tw < 4; tw++) \
        acc[tr][tw] = __builtin_amdgcn_mfma_f32_16x16x32_bf16( \
            af[tr], bf[tw], acc[tr][tw], 0, 0, 0); }

#define WAIT8  asm volatile("s_waitcnt vmcnt(8)" ::: "memory")
#define WAIT4  asm volatile("s_waitcnt vmcnt(4)" ::: "memory")
#define WAIT0  asm volatile("s_waitcnt vmcnt(0)" ::: "memory")
#define BAR    __builtin_amdgcn_s_barrier()

  STAGE(0, 0);                    // prologue: chunks 0,1 in flight
  STAGE(1, 1);
  #pragma unroll 1
  for (int k = 0; k < 10; k++){   // chunks 3k, 3k+1, 3k+2 in bufs 0,1,2
    const int c = 3 * k;
    STAGE(2, c + 2); WAIT8; BAR; COMPUTE(0); BAR;   // compute chunk c
    STAGE(0, c + 3); WAIT8; BAR; COMPUTE(1); BAR;   // chunk c+1
    STAGE(1, c + 4); WAIT8; BAR; COMPUTE(2); BAR;   // chunk c+2
  }
  WAIT4; BAR; COMPUTE(0); BAR;    // chunk 30
  WAIT0; BAR; COMPUTE(1);         // chunk 31

#undef STAGE
#undef LUNIT
#undef COMPUTE
#undef WAIT8
#undef WAIT4
#undef WAIT0
#undef BAR

  // C/D layout: col = lane&15, row = lhi*4 + j (validated R1-R14)
  #pragma unroll
  for (int tr = 0; tr < 4; tr++)
    #pragma unroll
    for (int tw = 0; tw < 4; tw++)
      #pragma unroll
      for (int j = 0; j < 4; j++){
        int m = m0 + wr * 64 + tr * 16 + lhi * 4 + j;
        int n = n0 + wc * 64 + tw * 16 + l15;
        __builtin_nontemporal_store(acc[tr][tw][j], &C[(size_t)m * NN + n]);
      }
}

// ---- reduction helpers (validated R1-R14) ----
template<int CTRL>
__device__ __forceinline__ float dpp_add(float x){
  int y = __builtin_amdgcn_mov_dpp(__float_as_int(x), CTRL, 0xF, 0xF, true);
  return x + __int_as_float(y);
}
__device__ __forceinline__ float q16sum(float x){
  x = dpp_add<0x121>(x);   // row_ror:1
  x = dpp_add<0x122>(x);   // row_ror:2
  x = dpp_add<0x124>(x);   // row_ror:4
  x = dpp_add<0x128>(x);   // row_ror:8
  return x;
}
__device__ __forceinline__ float pl16comb(float x){
  unsigned xi = __float_as_uint(x);
  uint2v r = __builtin_amdgcn_permlane16_swap(xi, xi, false, false);
  return __uint_as_float(r[0]) + __uint_as_float(r[1]);
}
__device__ __forceinline__ float pl32comb(float x){
  unsigned xi = __float_as_uint(x);
  uint2v r = __builtin_amdgcn_permlane32_swap(xi, xi, false, false);
  return __uint_as_float(r[0]) + __uint_as_float(r[1]);
}

// ---- sink2: pairs with clen <= 32 — slots 2,3 structurally zero, so the
// body is R11's minus those slots. Straight-line (no uniform branches) so
// p-arrays stay in VGPRs (R12/R14 lesson: any CFG around p => scratch). ----
__global__ __launch_bounds__(256) void sink2_kernel(
    const float* __restrict__ fg, const int* __restrict__ il,
    const int* __restrict__ cl, const int* __restrict__ rowoff,
    const int* __restrict__ coloff, const int* __restrict__ cnt,
    const int* __restrict__ list, float* __restrict__ out){
  const int lane = threadIdx.x & 63;
  const int s = blockIdx.x * 4 + (threadIdx.x >> 6);    // caption slot 0..127
  if (s >= cnt[0]) return;                              // wave-uniform exit
  const int c = __builtin_amdgcn_readfirstlane(list[s]);
  const int i = blockIdx.y;
  const int q = lane >> 4, t = lane & 15;

  const int ilen = __builtin_amdgcn_readfirstlane(il[i]);
  const int clen = __builtin_amdgcn_readfirstlane(cl[c]);
  const int ro   = __builtin_amdgcn_readfirstlane(rowoff[i]);
  const int co   = __builtin_amdgcn_readfirstlane(coloff[c]);
  const float* base = fg + (size_t)ro * NN + co;
  const float inv_il = __fdividef(1.0f, (float)ilen);
  const float inv_cl = __fdividef(1.0f, (float)clen);
  const bool v0 = (t < clen);
  const bool v1 = (t + 16 < clen);
  const int r0 = 9 * q;
  const int off0 = r0 * NN + t;

  float p0[9], p1[9];
  float ts = 0.f;
  #pragma unroll
  for (int k = 0; k < 9; k++){
    const bool rv = (r0 + k) < ilen;
    const float a0 = base[off0 + k * NN];
    const float a1 = base[off0 + k * NN + 16];
    p0[k] = (rv && v0) ? exp2f(fmaf(a0, L2E20, -L2E20)) : 0.f;
    p1[k] = (rv && v1) ? exp2f(fmaf(a1, L2E20, -L2E20)) : 0.f;
    ts += p0[k] + p1[k];
  }
  ts = q16sum(ts);
  ts = pl16comb(ts);
  ts = pl32comb(ts);
  const float sc = __fdividef(1.0f, ts + SEPS);
  #pragma unroll
  for (int k = 0; k < 9; k++){ p0[k] *= sc; p1[k] *= sc; }

  for (int it = 0; it < 3; it++){
    #pragma unroll
    for (int k = 0; k < 9; k++){
      float u = p0[k] + p1[k];
      u = q16sum(u);
      const float rs = __fdividef(inv_il, u + SEPS);
      p0[k] *= rs; p1[k] *= rs;
    }
    float s0 = 0.f, s1 = 0.f;
    #pragma unroll
    for (int k = 0; k < 9; k++){ s0 += p0[k]; s1 += p1[k]; }
    s0 = pl16comb(s0); s0 = pl32comb(s0);
    s1 = pl16comb(s1); s1 = pl32comb(s1);
    const float cs0 = __fdividef(inv_cl, s0 + SEPS);
    const float cs1 = __fdividef(inv_cl, s1 + SEPS);
    #pragma unroll
    for (int k = 0; k < 9; k++){ p0[k] *= cs0; p1[k] *= cs1; }
  }

  float sim = 0.f;
  #pragma unroll
  for (int k = 0; k < 9; k++){
    sim = fmaf(base[off0 + k * NN],      p0[k], sim);
    sim = fmaf(base[off0 + k * NN + 16], p1[k], sim);
  }
  sim = q16sum(sim);
  sim = pl16comb(sim);
  sim = pl32comb(sim);
  if (lane == 0) out[i * BT + c] = sim;
}

// ---- sink4: pairs with clen > 32 — EXACT R11 body (56 VGPR, no spill),
// with list indirection for the caption index. ----
__global__ __launch_bounds__(256) void sink4_kernel(
    const float* __restrict__ fg, const int* __restrict__ il,
    const int* __restrict__ cl, const int* __restrict__ rowoff,
    const int* __restrict__ coloff, const int* __restrict__ cnt,
    const int* __restrict__ list, float* __restrict__ out){
  const int lane = threadIdx.x & 63;
  const int s = blockIdx.x * 4 + (threadIdx.x >> 6);
  if (s >= cnt[0]) return;
  const int c = __builtin_amdgcn_readfirstlane(list[s]);
  const int i = blockIdx.y;
  const int q = lane >> 4, t = lane & 15;

  const int ilen = __builtin_amdgcn_readfirstlane(il[i]);
  const int clen = __builtin_amdgcn_readfirstlane(cl[c]);
  const int ro   = __builtin_amdgcn_readfirstlane(rowoff[i]);
  const int co   = __builtin_amdgcn_readfirstlane(coloff[c]);
  const float* base = fg + (size_t)ro * NN + co;
  const float inv_il = __fdividef(1.0f, (float)ilen);
  const float inv_cl = __fdividef(1.0f, (float)clen);
  const bool v0 = (t      < clen);
  const bool v1 = (t + 16 < clen);
  const bool v2 = (t + 32 < clen);
  const bool v3 = (t + 48 < clen);
  const int r0 = 9 * q;
  const int off0 = r0 * NN + t;

  float p0[9], p1[9], p2[9], p3[9];
  float ts = 0.f;
  #pragma unroll
  for (int k = 0; k < 9; k++){
    const bool rv = (r0 + k) < ilen;
    const float a0 = base[off0 + k * NN];
    const float a1 = base[off0 + k * NN + 16];
    const float a2 = base[off0 + k * NN + 32];
    const float a3 = base[off0 + k * NN + 48];
    p0[k] = (rv && v0) ? exp2f(fmaf(a0, L2E20, -L2E20)) : 0.f;
    p1[k] = (rv && v1) ? exp2f(fmaf(a1, L2E20, -L2E20)) : 0.f;
    p2[k] = (rv && v2) ? exp2f(fmaf(a2, L2E20, -L2E20)) : 0.f;
    p3[k] = (rv && v3) ? exp2f(fmaf(a3, L2E20, -L2E20)) : 0.f;
    ts += (p0[k] + p1[k]) + (p2[k] + p3[k]);
  }
  ts = q16sum(ts);
  ts = pl16comb(ts);
  ts = pl32comb(ts);
  const float sc = __fdividef(1.0f, ts + SEPS);
  #pragma unroll
  for (int k = 0; k < 9; k++){
    p0[k] *= sc; p1[k] *= sc; p2[k] *= sc; p3[k] *= sc;
  }

  for (int it = 0; it < 3; it++){
    #pragma unroll
    for (int k = 0; k < 9; k++){
      float u = (p0[k] + p1[k]) + (p2[k] + p3[k]);
      u = q16sum(u);
      const float rs = __fdividef(inv_il, u + SEPS);
      p0[k] *= rs; p1[k] *= rs; p2[k] *= rs; p3[k] *= rs;
    }
    float s0 = 0.f, s1 = 0.f, s2 = 0.f, s3 = 0.f;
    #pragma unroll
    for (int k = 0; k < 9; k++){
      s0 += p0[k]; s1 += p1[k]; s2 += p2[k]; s3 += p3[k];
    }
    s0 = pl16comb(s0); s0 = pl32comb(s0);
    s1 = pl16comb(s1); s1 = pl32comb(s1);
    s2 = pl16comb(s2); s2 = pl32comb(s2);
    s3 = pl16comb(s3); s3 = pl32comb(s3);
    const float cs0 = __fdividef(inv_cl, s0 + SEPS);
    const float cs1 = __fdividef(inv_cl, s1 + SEPS);
    const float cs2 = __fdividef(inv_cl, s2 + SEPS);
    const float cs3 = __fdividef(inv_cl, s3 + SEPS);
    #pragma unroll
    for (int k = 0; k < 9; k++){
      p0[k] *= cs0; p1[k] *= cs1; p2[k] *= cs2; p3[k] *= cs3;
    }
  }

  float sim = 0.f;
  #pragma unroll
  for (int k = 0; k < 9; k++){
    sim = fmaf(base[off0 + k * NN],      p0[k], sim);
    sim = fmaf(base[off0 + k * NN + 16], p1[k], sim);
    sim = fmaf(base[off0 + k * NN + 32], p2[k], sim);
    sim = fmaf(base[off0 + k * NN + 48], p3[k], sim);
  }
  sim = q16sum(sim);
  sim = pl16comb(sim);
  sim = pl32comb(sim);
  if (lane == 0) out[i * BT + c] = sim;
}

extern "C" void kernel_launch(void* const* d_in, const int* in_sizes, int n_in,
                              void* d_out, int out_size, void* d_ws, size_t ws_size,
                              hipStream_t stream){
  const float* imgs = (const float*)d_in[0];
  const float* caps = (const float*)d_in[1];
  const int* il = (const int*)d_in[2];
  const int* cl = (const int*)d_in[3];
  float* out = (float*)d_out;

  unsigned short* Ab = (unsigned short*)d_ws;               // [4608][1024] bf16
  unsigned short* Bb = Ab + (size_t)BI * RR * DD;           // [6400][1024] bf16
  float* fg = (float*)(Bb + (size_t)BT * WW * DD);          // [4608][6400] f32
  int* rowoff = (int*)(fg + (size_t)BI * RR * NN);          // [129]
  int* coloff = rowoff + 129;                               // [129]
  int* cnts   = coloff + 129;                               // [2]
  int* listA  = cnts + 2;                                   // [128]
  int* listB  = listA + 128;                                // [128]

  prefix_kernel<<<1, 256, 0, stream>>>(il, cl, rowoff, coloff, cnts, listA, listB);
  gather_cvt_kernel<<<BI * RR + BT * WW, 256, 0, stream>>>(
      imgs, caps, il, cl, rowoff, coloff, Ab, Bb);
  gemm_kernel<<<36 * 50, 256, 0, stream>>>(Ab, Bb, rowoff, coloff, fg);
  sink2_kernel<<<dim3(32, BI), 256, 0, stream>>>(
      fg, il, cl, rowoff, coloff, cnts + 0, listA, out);
  sink4_kernel<<<dim3(32, BI), 256, 0, stream>>>(
      fg, il, cl, rowoff, coloff, cnts + 1, listB, out);
}

// Round 16
// 113.044 us; speedup vs baseline: 1.2656x; 1.2656x over previous
//
#include <hip/hip_runtime.h>
#include <stdint.h>

#define BI 128
#define BT 128
#define RR 36
#define WW 50
#define DD 1024
#define NN 6400       /* fg row stride, static */
#define SEPS 1e-6f
#define L2E20 28.853900817779268f   /* 20/ln2 */

typedef __attribute__((ext_vector_type(8))) short short8v;
typedef __attribute__((ext_vector_type(4))) float float4v;
typedef __attribute__((ext_vector_type(2))) unsigned int uint2v;

__device__ __forceinline__ unsigned short f2bf(float f){
  unsigned u = __float_as_uint(f);
  return (unsigned short)((u + 0x7FFFu + ((u >> 16) & 1u)) >> 16);
}

// ---- exclusive prefix scan of il (128) and cl (128); dst[128] = total ----
__global__ __launch_bounds__(256) void prefix_kernel(
    const int* __restrict__ il, const int* __restrict__ cl,
    int* __restrict__ rowoff, int* __restrict__ coloff){
  __shared__ int buf[2][128];
  const int t = threadIdx.x;
  const int which = t >> 7, j = t & 127;
  const int v = which ? cl[j] : il[j];
  buf[which][j] = v;
  __syncthreads();
  #pragma unroll
  for (int off = 1; off < 128; off <<= 1){
    int x = (j >= off) ? buf[which][j - off] : 0;
    __syncthreads();
    buf[which][j] += x;
    __syncthreads();
  }
  int* dst = which ? coloff : rowoff;
  dst[j] = buf[which][j] - v;                 // exclusive
  if (j == 127) dst[128] = buf[which][127];   // total (M' / N')
}

// ---- gather valid rows + f32->bf16 convert. Block = one source row. ----
__global__ __launch_bounds__(256) void gather_cvt_kernel(
    const float* __restrict__ imgs, const float* __restrict__ caps,
    const int* __restrict__ il, const int* __restrict__ cl,
    const int* __restrict__ rowoff, const int* __restrict__ coloff,
    unsigned short* __restrict__ Ab, unsigned short* __restrict__ Bb){
  const int b = blockIdx.x;
  const int t = threadIdx.x;
  if (b < BI * RR){
    const int i = b / RR, r = b % RR;
    if (r >= il[i]) return;
    const float4 v = *(const float4*)(imgs + (size_t)b * DD + t * 4);
    ushort4 o = make_ushort4(f2bf(v.x), f2bf(v.y), f2bf(v.z), f2bf(v.w));
    *(ushort4*)(Ab + (size_t)(rowoff[i] + r) * DD + t * 4) = o;
  } else {
    const int bb = b - BI * RR;
    const int c = bb / WW, w = bb % WW;
    if (w >= cl[c]) return;
    const float4 v = *(const float4*)(caps + (size_t)bb * DD + t * 4);
    ushort4 o = make_ushort4(f2bf(v.x), f2bf(v.y), f2bf(v.z), f2bf(v.w));
    *(ushort4*)(Bb + (size_t)(coloff[c] + w) * DD + t * 4) = o;
  }
}

// ---- 128x64 GEMM tiles, BK=32, triple-buffered LDS (3 x 12KB = 36KB),
// depth-2 prefetch (3 loads/thread/stage -> steady-state vmcnt(6)).
// R16: halved N-tile doubles active blocks 644->1265 (~16 waves/CU vs ~10)
// to attack the latency-bound stall (R8-R10: MfmaUtil 14%, 2.5 blocks/CU).
// Buffer layout: A = 512 units x 16B (8KB), B = 256 units at +8192.
// Row-pair bank swizzle + compact grid + NT C-stores (validated R9-R11). ----
__global__ __launch_bounds__(256) void gemm_kernel(
    const unsigned short* __restrict__ A, const unsigned short* __restrict__ B,
    const int* __restrict__ rowoff, const int* __restrict__ coloff,
    float* __restrict__ C){
  __shared__ __align__(16) unsigned char LDS[36864];
  const int Mp = rowoff[BI];                      // M' (runtime)
  const int Np = coloff[BT];                      // N'
  const int nnb = (Np + 63) >> 6;
  const int nact = ((Mp + 127) >> 7) * nnb;
  const int bx = blockIdx.x;
  if (bx >= nact) return;                         // compact early-exit
  const int mb = bx / nnb, nb = bx - mb * nnb;
  const int m0 = mb * 128, n0 = nb * 64;

  const int tid = threadIdx.x;
  const int lane = tid & 63, wv = tid >> 6;
  const int l15 = lane & 15, lhi = lane >> 4;
  const int wr = wv >> 1, wc = wv & 1;            // 2x2 wave grid, 64x32/wave

  // staging sources: 3 units/thread/chunk (u = j*256+tid; A: u<512, B: else)
  const unsigned short* sp[3];
  #pragma unroll
  for (int j = 0; j < 3; j++){
    const int u = j * 256 + tid;
    const int v = (u < 512) ? u : (u - 512);
    const int sup = v >> 3, slot = v & 7;
    const int sub = slot ^ (sup & 7);             // inverse of store swizzle
    const int row = sup * 2 + (sub >> 2);
    const int kg  = sub & 3;
    sp[j] = ((u < 512) ? (A + (size_t)(m0 + row) * DD)
                       : (B + (size_t)(n0 + row) * DD)) + kg * 8;
  }

  float4v acc[4][2];
  #pragma unroll
  for (int a1 = 0; a1 < 4; a1++)
    #pragma unroll
    for (int b1 = 0; b1 < 2; b1++)
      acc[a1][b1] = (float4v){0.f, 0.f, 0.f, 0.f};

#define STAGE(BUF, CH) { \
    _Pragma("unroll") \
    for (int j = 0; j < 3; j++) \
      __builtin_amdgcn_global_load_lds( \
          (const __attribute__((address_space(1))) void*)(sp[j] + (CH) * 32), \
          (__attribute__((address_space(3))) void*)(LDS + (BUF) * 12288 + (j * 256 + tid) * 16), \
          16, 0, 0); }

#define LUNIT(row) (((row) >> 1) * 8 + (((((row) & 1) << 2) + lhi) ^ (((row) >> 1) & 7)))

#define COMPUTE(BUF) { \
    short8v af[4], bf[2]; \
    _Pragma("unroll") \
    for (int tr = 0; tr < 4; tr++){ \
      const int row = wr * 64 + tr * 16 + l15; \
      af[tr] = *(const short8v*)(LDS + (BUF) * 12288 + LUNIT(row) * 16); \
    } \
    _Pragma("unroll") \
    for (int tw = 0; tw < 2; tw++){ \
      const int row = wc * 32 + tw * 16 + l15; \
      bf[tw] = *(const short8v*)(LDS + (BUF) * 12288 + 8192 + LUNIT(row) * 16); \
    } \
    _Pragma("unroll") \
    for (int tr = 0; tr < 4; tr++) \
      _Pragma("unroll") \
      for (int tw = 0; tw < 2; tw++) \
        acc[tr][tw] = __builtin_amdgcn_mfma_f32_16x16x32_bf16( \
            af[tr], bf[tw], acc[tr][tw], 0, 0, 0); }

#define WAIT6  asm volatile("s_waitcnt vmcnt(6)" ::: "memory")
#define WAIT3  asm volatile("s_waitcnt vmcnt(3)" ::: "memory")
#define WAIT0  asm volatile("s_waitcnt vmcnt(0)" ::: "memory")
#define BAR    __builtin_amdgcn_s_barrier()

  STAGE(0, 0);                    // prologue: chunks 0,1 in flight
  STAGE(1, 1);
  #pragma unroll 1
  for (int k = 0; k < 10; k++){   // chunks 3k..3k+2 in bufs 0,1,2
    const int c = 3 * k;
    STAGE(2, c + 2); WAIT6; BAR; COMPUTE(0); BAR;   // chunk c
    STAGE(0, c + 3); WAIT6; BAR; COMPUTE(1); BAR;   // chunk c+1
    STAGE(1, c + 4); WAIT6; BAR; COMPUTE(2); BAR;   // chunk c+2
  }
  WAIT3; BAR; COMPUTE(0); BAR;    // chunk 30 (staged at k=9 step B)
  WAIT0; BAR; COMPUTE(1);         // chunk 31 (staged at k=9 step C)

#undef STAGE
#undef LUNIT
#undef COMPUTE
#undef WAIT6
#undef WAIT3
#undef WAIT0
#undef BAR

  // C/D layout: col = lane&15, row = lhi*4 + j (m89/m91, validated R1-R15).
  // Non-temporal: fg is consumed once, later, by sink — keep it out of L2.
  #pragma unroll
  for (int tr = 0; tr < 4; tr++)
    #pragma unroll
    for (int tw = 0; tw < 2; tw++)
      #pragma unroll
      for (int j = 0; j < 4; j++){
        int m = m0 + wr * 64 + tr * 16 + lhi * 4 + j;
        int n = n0 + wc * 32 + tw * 16 + l15;
        __builtin_nontemporal_store(acc[tr][tw][j], &C[(size_t)m * NN + n]);
      }
}

// ---- reduction helpers (validated R1-R15) ----
template<int CTRL>
__device__ __forceinline__ float dpp_add(float x){
  int y = __builtin_amdgcn_mov_dpp(__float_as_int(x), CTRL, 0xF, 0xF, true);
  return x + __int_as_float(y);
}
__device__ __forceinline__ float q16sum(float x){
  x = dpp_add<0x121>(x);   // row_ror:1
  x = dpp_add<0x122>(x);   // row_ror:2
  x = dpp_add<0x124>(x);   // row_ror:4
  x = dpp_add<0x128>(x);   // row_ror:8
  return x;
}
__device__ __forceinline__ float pl16comb(float x){
  unsigned xi = __float_as_uint(x);
  uint2v r = __builtin_amdgcn_permlane16_swap(xi, xi, false, false);
  return __uint_as_float(r[0]) + __uint_as_float(r[1]);
}
__device__ __forceinline__ float pl32comb(float x){
  unsigned xi = __float_as_uint(x);
  uint2v r = __builtin_amdgcn_permlane32_swap(xi, xi, false, false);
  return __uint_as_float(r[0]) + __uint_as_float(r[1]);
}

// ---- Sinkhorn: EXACT R11 body (56 VGPR, no spill, 75% VALUBusy — the
// proven-stable optimum; R12-R15 alternatives all spilled or lost TLP).
// ONE pair per wave; quarter q owns rows 9q..9q+8; lane (q,t) holds cols
// t, t+16, t+32, t+48. Fully straight-line. ----
__global__ __launch_bounds__(256) void sink_kernel(
    const float* __restrict__ fg, const int* __restrict__ il,
    const int* __restrict__ cl, const int* __restrict__ rowoff,
    const int* __restrict__ coloff, float* __restrict__ out){
  const int lane = threadIdx.x & 63;
  const int gw = blockIdx.x * 4 + (threadIdx.x >> 6);   // 16384 waves
  const int i = gw >> 7, c = gw & 127;
  const int q = lane >> 4, t = lane & 15;

  const int ilen = __builtin_amdgcn_readfirstlane(il[i]);
  const int clen = __builtin_amdgcn_readfirstlane(cl[c]);
  const int ro   = __builtin_amdgcn_readfirstlane(rowoff[i]);
  const int co   = __builtin_amdgcn_readfirstlane(coloff[c]);
  const float* base = fg + (size_t)ro * NN + co;        // wave-uniform (saddr)
  const float inv_il = __fdividef(1.0f, (float)ilen);
  const float inv_cl = __fdividef(1.0f, (float)clen);
  const bool v0 = (t      < clen);
  const bool v1 = (t + 16 < clen);
  const bool v2 = (t + 32 < clen);
  const bool v3 = (t + 48 < clen);
  const int r0 = 9 * q;                                 // this quarter's rows
  const int off0 = r0 * NN + t;                         // 32-bit elem offset

  float p0[9], p1[9], p2[9], p3[9];
  float ts = 0.f;
  #pragma unroll
  for (int k = 0; k < 9; k++){
    const bool rv = (r0 + k) < ilen;
    const float a0 = base[off0 + k * NN];
    const float a1 = base[off0 + k * NN + 16];
    const float a2 = base[off0 + k * NN + 32];
    const float a3 = base[off0 + k * NN + 48];
    p0[k] = (rv && v0) ? exp2f(fmaf(a0, L2E20, -L2E20)) : 0.f;
    p1[k] = (rv && v1) ? exp2f(fmaf(a1, L2E20, -L2E20)) : 0.f;
    p2[k] = (rv && v2) ? exp2f(fmaf(a2, L2E20, -L2E20)) : 0.f;
    p3[k] = (rv && v3) ? exp2f(fmaf(a3, L2E20, -L2E20)) : 0.f;
    ts += (p0[k] + p1[k]) + (p2[k] + p3[k]);
  }
  ts = q16sum(ts);
  ts = pl16comb(ts);
  ts = pl32comb(ts);
  const float sc = __fdividef(1.0f, ts + SEPS);         // P /= (sum + EPS)
  #pragma unroll
  for (int k = 0; k < 9; k++){
    p0[k] *= sc; p1[k] *= sc; p2[k] *= sc; p3[k] *= sc;
  }

  for (int it = 0; it < 3; it++){
    #pragma unroll
    for (int k = 0; k < 9; k++){                        // u = rowsum + EPS
      float u = (p0[k] + p1[k]) + (p2[k] + p3[k]);
      u = q16sum(u);
      const float rs = __fdividef(inv_il, u + SEPS);
      p0[k] *= rs; p1[k] *= rs; p2[k] *= rs; p3[k] *= rs;
    }
    float s0 = 0.f, s1 = 0.f, s2 = 0.f, s3 = 0.f;       // colsums (in-lane)
    #pragma unroll
    for (int k = 0; k < 9; k++){
      s0 += p0[k]; s1 += p1[k]; s2 += p2[k]; s3 += p3[k];
    }
    s0 = pl16comb(s0); s0 = pl32comb(s0);
    s1 = pl16comb(s1); s1 = pl32comb(s1);
    s2 = pl16comb(s2); s2 = pl32comb(s2);
    s3 = pl16comb(s3); s3 = pl32comb(s3);
    const float cs0 = __fdividef(inv_cl, s0 + SEPS);
    const float cs1 = __fdividef(inv_cl, s1 + SEPS);
    const float cs2 = __fdividef(inv_cl, s2 + SEPS);
    const float cs3 = __fdividef(inv_cl, s3 + SEPS);
    #pragma unroll
    for (int k = 0; k < 9; k++){
      p0[k] *= cs0; p1[k] *= cs1; p2[k] *= cs2; p3[k] *= cs3;
    }
  }

  float sim = 0.f;
  #pragma unroll
  for (int k = 0; k < 9; k++){                          // reload f (L3-hot)
    sim = fmaf(base[off0 + k * NN],      p0[k], sim);
    sim = fmaf(base[off0 + k * NN + 16], p1[k], sim);
    sim = fmaf(base[off0 + k * NN + 32], p2[k], sim);
    sim = fmaf(base[off0 + k * NN + 48], p3[k], sim);
  }
  sim = q16sum(sim);
  sim = pl16comb(sim);
  sim = pl32comb(sim);
  if (lane == 0) out[i * BT + c] = sim;
}

extern "C" void kernel_launch(void* const* d_in, const int* in_sizes, int n_in,
                              void* d_out, int out_size, void* d_ws, size_t ws_size,
                              hipStream_t stream){
  const float* imgs = (const float*)d_in[0];
  const float* caps = (const float*)d_in[1];
  const int* il = (const int*)d_in[2];
  const int* cl = (const int*)d_in[3];
  float* out = (float*)d_out;

  unsigned short* Ab = (unsigned short*)d_ws;               // [4608][1024] bf16
  unsigned short* Bb = Ab + (size_t)BI * RR * DD;           // [6400][1024] bf16
  float* fg = (float*)(Bb + (size_t)BT * WW * DD);          // [4608][6400] f32
  int* rowoff = (int*)(fg + (size_t)BI * RR * NN);          // [129]
  int* coloff = rowoff + 129;                               // [129]

  prefix_kernel<<<1, 256, 0, stream>>>(il, cl, rowoff, coloff);
  gather_cvt_kernel<<<BI * RR + BT * WW, 256, 0, stream>>>(
      imgs, caps, il, cl, rowoff, coloff, Ab, Bb);
  gemm_kernel<<<36 * 100, 256, 0, stream>>>(Ab, Bb, rowoff, coloff, fg);
  sink_kernel<<<(BI * BT) / 4, 256, 0, stream>>>(fg, il, cl, rowoff, coloff, out);
}

// Round 17
// 105.720 us; speedup vs baseline: 1.3533x; 1.0693x over previous
//
#include <hip/hip_runtime.h>
#include <stdint.h>

#define BI 128
#define BT 128
#define RR 36
#define WW 50
#define DD 1024
#define NN 6400       /* fg row stride, static */
#define SEPS 1e-6f
#define L2E20 28.853900817779268f   /* 20/ln2 */

typedef __attribute__((ext_vector_type(8))) short short8v;
typedef __attribute__((ext_vector_type(4))) float float4v;
typedef __attribute__((ext_vector_type(2))) unsigned int uint2v;

__device__ __forceinline__ unsigned short f2bf(float f){
  unsigned u = __float_as_uint(f);
  return (unsigned short)((u + 0x7FFFu + ((u >> 16) & 1u)) >> 16);
}

// ---- integer wave-wide sum (same lane movement as the float version
// validated R8-R16: 4 DPP row_ror + permlane16_swap + permlane32_swap) ----
template<int CTRL>
__device__ __forceinline__ int dpp_addi(int x){
  int y = __builtin_amdgcn_mov_dpp(x, CTRL, 0xF, 0xF, true);
  return x + y;
}
__device__ __forceinline__ int iwaveSum(int x){
  x = dpp_addi<0x121>(x);
  x = dpp_addi<0x122>(x);
  x = dpp_addi<0x124>(x);
  x = dpp_addi<0x128>(x);
  {
    uint2v r = __builtin_amdgcn_permlane16_swap((unsigned)x, (unsigned)x, false, false);
    x = (int)r[0] + (int)r[1];
  }
  {
    uint2v r = __builtin_amdgcn_permlane32_swap((unsigned)x, (unsigned)x, false, false);
    x = (int)r[0] + (int)r[1];
  }
  return x;
}
// sum of v[j] for j < lim, v has 128 entries; every lane returns the total.
__device__ __forceinline__ int maskedSum128(const int* __restrict__ v,
                                            int lim, int lane){
  const int a = v[2 * lane];
  const int b = v[2 * lane + 1];
  int s = ((2 * lane) < lim ? a : 0) + ((2 * lane + 1) < lim ? b : 0);
  return iwaveSum(s);
}

// ---- gather valid rows + f32->bf16 convert. Block = one source row.
// R17: computes its own destination offset (prefix kernel eliminated). ----
__global__ __launch_bounds__(256) void gather_cvt_kernel(
    const float* __restrict__ imgs, const float* __restrict__ caps,
    const int* __restrict__ il, const int* __restrict__ cl,
    unsigned short* __restrict__ Ab, unsigned short* __restrict__ Bb){
  const int b = blockIdx.x;
  const int t = threadIdx.x;
  const int lane = t & 63;
  if (b < BI * RR){
    const int i = b / RR, r = b % RR;
    if (r >= il[i]) return;                       // block-uniform
    const int ro = maskedSum128(il, i, lane);     // rowoff[i], wave-computed
    const float4 v = *(const float4*)(imgs + (size_t)b * DD + t * 4);
    ushort4 o = make_ushort4(f2bf(v.x), f2bf(v.y), f2bf(v.z), f2bf(v.w));
    *(ushort4*)(Ab + (size_t)(ro + r) * DD + t * 4) = o;
  } else {
    const int bb = b - BI * RR;
    const int c = bb / WW, w = bb % WW;
    if (w >= cl[c]) return;
    const int co = maskedSum128(cl, c, lane);     // coloff[c]
    const float4 v = *(const float4*)(caps + (size_t)bb * DD + t * 4);
    ushort4 o = make_ushort4(f2bf(v.x), f2bf(v.y), f2bf(v.z), f2bf(v.w));
    *(ushort4*)(Bb + (size_t)(co + w) * DD + t * 4) = o;
  }
}

// ---- 128x128 GEMM, BK=32, triple-buffered LDS, depth-2 prefetch, compact
// grid + non-temporal C stores (validated R11; R16 showed 128x64 is worse).
// R17: Mp/Np computed in-kernel (totals only). ----
__global__ __launch_bounds__(256) void gemm_kernel(
    const unsigned short* __restrict__ A, const unsigned short* __restrict__ B,
    const int* __restrict__ il, const int* __restrict__ cl,
    float* __restrict__ C){
  __shared__ __align__(16) unsigned char LDS[49152];
  const int tid = threadIdx.x;
  const int lane = tid & 63, wv = tid >> 6;
  const int Mp = __builtin_amdgcn_readfirstlane(maskedSum128(il, BI, lane));
  const int Np = __builtin_amdgcn_readfirstlane(maskedSum128(cl, BT, lane));
  const int nnb = (Np + 127) >> 7;
  const int nact = ((Mp + 127) >> 7) * nnb;
  const int bx = blockIdx.x;
  if (bx >= nact) return;                         // compact early-exit
  const int mb = bx / nnb, nb = bx - mb * nnb;
  const int m0 = mb * 128, n0 = nb * 128;

  const int l15 = lane & 15, lhi = lane >> 4;
  const int wr = wv >> 1, wc = wv & 1;            // 2x2 wave grid, 64x64/wave

  // staging sources: 4 units/thread/chunk (u = j*256+tid; A: u<512, B: u>=512)
  const unsigned short* sp[4];
  #pragma unroll
  for (int j = 0; j < 4; j++){
    const int u = j * 256 + tid;
    const int v = u & 511;
    const int sup = v >> 3, slot = v & 7;
    const int sub = slot ^ (sup & 7);             // inverse of store swizzle
    const int row = sup * 2 + (sub >> 2);
    const int kg  = sub & 3;
    sp[j] = ((u < 512) ? (A + (size_t)(m0 + row) * DD)
                       : (B + (size_t)(n0 + row) * DD)) + kg * 8;
  }

  float4v acc[4][4];
  #pragma unroll
  for (int a1 = 0; a1 < 4; a1++)
    #pragma unroll
    for (int b1 = 0; b1 < 4; b1++)
      acc[a1][b1] = (float4v){0.f, 0.f, 0.f, 0.f};

#define STAGE(BUF, CH) { \
    _Pragma("unroll") \
    for (int j = 0; j < 4; j++) \
      __builtin_amdgcn_global_load_lds( \
          (const __attribute__((address_space(1))) void*)(sp[j] + (CH) * 32), \
          (__attribute__((address_space(3))) void*)(LDS + (BUF) * 16384 + (j * 256 + tid) * 16), \
          16, 0, 0); }

#define LUNIT(row) (((row) >> 1) * 8 + (((((row) & 1) << 2) + lhi) ^ (((row) >> 1) & 7)))

#define COMPUTE(BUF) { \
    short8v af[4], bf[4]; \
    _Pragma("unroll") \
    for (int tr = 0; tr < 4; tr++){ \
      const int row = wr * 64 + tr * 16 + l15; \
      af[tr] = *(const short8v*)(LDS + (BUF) * 16384 + LUNIT(row) * 16); \
    } \
    _Pragma("unroll") \
    for (int tw = 0; tw < 4; tw++){ \
      const int row = wc * 64 + tw * 16 + l15; \
      bf[tw] = *(const short8v*)(LDS + (BUF) * 16384 + 8192 + LUNIT(row) * 16); \
    } \
    _Pragma("unroll") \
    for (int tr = 0; tr < 4; tr++) \
      _Pragma("unroll") \
      for (int tw = 0; tw < 4; tw++) \
        acc[tr][tw] = __builtin_amdgcn_mfma_f32_16x16x32_bf16( \
            af[tr], bf[tw], acc[tr][tw], 0, 0, 0); }

#define WAIT8  asm volatile("s_waitcnt vmcnt(8)" ::: "memory")
#define WAIT4  asm volatile("s_waitcnt vmcnt(4)" ::: "memory")
#define WAIT0  asm volatile("s_waitcnt vmcnt(0)" ::: "memory")
#define BAR    __builtin_amdgcn_s_barrier()

  STAGE(0, 0);                    // prologue: chunks 0,1 in flight
  STAGE(1, 1);
  #pragma unroll 1
  for (int k = 0; k < 10; k++){   // chunks 3k, 3k+1, 3k+2 in bufs 0,1,2
    const int c = 3 * k;
    STAGE(2, c + 2); WAIT8; BAR; COMPUTE(0); BAR;   // compute chunk c
    STAGE(0, c + 3); WAIT8; BAR; COMPUTE(1); BAR;   // chunk c+1
    STAGE(1, c + 4); WAIT8; BAR; COMPUTE(2); BAR;   // chunk c+2
  }
  WAIT4; BAR; COMPUTE(0); BAR;    // chunk 30 (staged at k=9 step B)
  WAIT0; BAR; COMPUTE(1);         // chunk 31 (staged at k=9 step C)

#undef STAGE
#undef LUNIT
#undef COMPUTE
#undef WAIT8
#undef WAIT4
#undef WAIT0
#undef BAR

  // C/D layout: col = lane&15, row = lhi*4 + j (m89/m91, validated R1-R16).
  // Non-temporal: fg is consumed once, later, by sink — keep it out of L2.
  #pragma unroll
  for (int tr = 0; tr < 4; tr++)
    #pragma unroll
    for (int tw = 0; tw < 4; tw++)
      #pragma unroll
      for (int j = 0; j < 4; j++){
        int m = m0 + wr * 64 + tr * 16 + lhi * 4 + j;
        int n = n0 + wc * 64 + tw * 16 + l15;
        __builtin_nontemporal_store(acc[tr][tw][j], &C[(size_t)m * NN + n]);
      }
}

// ---- float reduction helpers (validated R1-R16) ----
template<int CTRL>
__device__ __forceinline__ float dpp_add(float x){
  int y = __builtin_amdgcn_mov_dpp(__float_as_int(x), CTRL, 0xF, 0xF, true);
  return x + __int_as_float(y);
}
__device__ __forceinline__ float q16sum(float x){
  x = dpp_add<0x121>(x);   // row_ror:1
  x = dpp_add<0x122>(x);   // row_ror:2
  x = dpp_add<0x124>(x);   // row_ror:4
  x = dpp_add<0x128>(x);   // row_ror:8
  return x;
}
__device__ __forceinline__ float pl16comb(float x){
  unsigned xi = __float_as_uint(x);
  uint2v r = __builtin_amdgcn_permlane16_swap(xi, xi, false, false);
  return __uint_as_float(r[0]) + __uint_as_float(r[1]);
}
__device__ __forceinline__ float pl32comb(float x){
  unsigned xi = __float_as_uint(x);
  uint2v r = __builtin_amdgcn_permlane32_swap(xi, xi, false, false);
  return __uint_as_float(r[0]) + __uint_as_float(r[1]);
}

// ---- Sinkhorn: EXACT R11 body (56 VGPR, no spill, 75% VALUBusy — the
// proven-stable optimum across R12-R15 alternatives). ONE pair per wave;
// quarter q owns rows 9q..9q+8; lane (q,t) holds cols t,t+16,t+32,t+48.
// R17: rowoff/coloff computed in-wave (prefix kernel eliminated). ----
__global__ __launch_bounds__(256) void sink_kernel(
    const float* __restrict__ fg, const int* __restrict__ il,
    const int* __restrict__ cl, float* __restrict__ out){
  const int lane = threadIdx.x & 63;
  const int gw = blockIdx.x * 4 + (threadIdx.x >> 6);   // 16384 waves
  const int i = gw >> 7, c = gw & 127;
  const int q = lane >> 4, t = lane & 15;

  const int ilen = __builtin_amdgcn_readfirstlane(il[i]);
  const int clen = __builtin_amdgcn_readfirstlane(cl[c]);
  const int ro   = __builtin_amdgcn_readfirstlane(maskedSum128(il, i, lane));
  const int co   = __builtin_amdgcn_readfirstlane(maskedSum128(cl, c, lane));
  const float* base = fg + (size_t)ro * NN + co;        // wave-uniform (saddr)
  const float inv_il = __fdividef(1.0f, (float)ilen);
  const float inv_cl = __fdividef(1.0f, (float)clen);
  const bool v0 = (t      < clen);
  const bool v1 = (t + 16 < clen);
  const bool v2 = (t + 32 < clen);
  const bool v3 = (t + 48 < clen);
  const int r0 = 9 * q;                                 // this quarter's rows
  const int off0 = r0 * NN + t;                         // 32-bit elem offset

  float p0[9], p1[9], p2[9], p3[9];
  float ts = 0.f;
  #pragma unroll
  for (int k = 0; k < 9; k++){
    const bool rv = (r0 + k) < ilen;
    const float a0 = base[off0 + k * NN];
    const float a1 = base[off0 + k * NN + 16];
    const float a2 = base[off0 + k * NN + 32];
    const float a3 = base[off0 + k * NN + 48];
    p0[k] = (rv && v0) ? exp2f(fmaf(a0, L2E20, -L2E20)) : 0.f;
    p1[k] = (rv && v1) ? exp2f(fmaf(a1, L2E20, -L2E20)) : 0.f;
    p2[k] = (rv && v2) ? exp2f(fmaf(a2, L2E20, -L2E20)) : 0.f;
    p3[k] = (rv && v3) ? exp2f(fmaf(a3, L2E20, -L2E20)) : 0.f;
    ts += (p0[k] + p1[k]) + (p2[k] + p3[k]);
  }
  ts = q16sum(ts);
  ts = pl16comb(ts);
  ts = pl32comb(ts);
  const float sc = __fdividef(1.0f, ts + SEPS);         // P /= (sum + EPS)
  #pragma unroll
  for (int k = 0; k < 9; k++){
    p0[k] *= sc; p1[k] *= sc; p2[k] *= sc; p3[k] *= sc;
  }

  for (int it = 0; it < 3; it++){
    #pragma unroll
    for (int k = 0; k < 9; k++){                        // u = rowsum + EPS
      float u = (p0[k] + p1[k]) + (p2[k] + p3[k]);
      u = q16sum(u);
      const float rs = __fdividef(inv_il, u + SEPS);
      p0[k] *= rs; p1[k] *= rs; p2[k] *= rs; p3[k] *= rs;
    }
    float s0 = 0.f, s1 = 0.f, s2 = 0.f, s3 = 0.f;       // colsums (in-lane)
    #pragma unroll
    for (int k = 0; k < 9; k++){
      s0 += p0[k]; s1 += p1[k]; s2 += p2[k]; s3 += p3[k];
    }
    s0 = pl16comb(s0); s0 = pl32comb(s0);
    s1 = pl16comb(s1); s1 = pl32comb(s1);
    s2 = pl16comb(s2); s2 = pl32comb(s2);
    s3 = pl16comb(s3); s3 = pl32comb(s3);
    const float cs0 = __fdividef(inv_cl, s0 + SEPS);
    const float cs1 = __fdividef(inv_cl, s1 + SEPS);
    const float cs2 = __fdividef(inv_cl, s2 + SEPS);
    const float cs3 = __fdividef(inv_cl, s3 + SEPS);
    #pragma unroll
    for (int k = 0; k < 9; k++){
      p0[k] *= cs0; p1[k] *= cs1; p2[k] *= cs2; p3[k] *= cs3;
    }
  }

  float sim = 0.f;
  #pragma unroll
  for (int k = 0; k < 9; k++){                          // reload f (L3-hot)
    sim = fmaf(base[off0 + k * NN],      p0[k], sim);
    sim = fmaf(base[off0 + k * NN + 16], p1[k], sim);
    sim = fmaf(base[off0 + k * NN + 32], p2[k], sim);
    sim = fmaf(base[off0 + k * NN + 48], p3[k], sim);
  }
  sim = q16sum(sim);
  sim = pl16comb(sim);
  sim = pl32comb(sim);
  if (lane == 0) out[i * BT + c] = sim;
}

extern "C" void kernel_launch(void* const* d_in, const int* in_sizes, int n_in,
                              void* d_out, int out_size, void* d_ws, size_t ws_size,
                              hipStream_t stream){
  const float* imgs = (const float*)d_in[0];
  const float* caps = (const float*)d_in[1];
  const int* il = (const int*)d_in[2];
  const int* cl = (const int*)d_in[3];
  float* out = (float*)d_out;

  unsigned short* Ab = (unsigned short*)d_ws;               // [4608][1024] bf16
  unsigned short* Bb = Ab + (size_t)BI * RR * DD;           // [6400][1024] bf16
  float* fg = (float*)(Bb + (size_t)BT * WW * DD);          // [4608][6400] f32

  gather_cvt_kernel<<<BI * RR + BT * WW, 256, 0, stream>>>(
      imgs, caps, il, cl, Ab, Bb);
  gemm_kernel<<<36 * 50, 256, 0, stream>>>(Ab, Bb, il, cl, fg);
  sink_kernel<<<(BI * BT) / 4, 256, 0, stream>>>(fg, il, cl, out);
}

// Round 18
// 95.658 us; speedup vs baseline: 1.4957x; 1.1052x over previous
//
#include <hip/hip_runtime.h>
#include <stdint.h>

#define BI 128
#define BT 128
#define RR 36
#define WW 50
#define DD 1024
#define NN 6400       /* fg row stride, static */
#define SEPS 1e-6f
#define L2E20 28.853900817779268f   /* 20/ln2 */

typedef __attribute__((ext_vector_type(8))) short short8v;
typedef __attribute__((ext_vector_type(4))) float float4v;
typedef __attribute__((ext_vector_type(2))) unsigned int uint2v;

__device__ __forceinline__ unsigned short f2bf(float f){
  unsigned u = __float_as_uint(f);
  return (unsigned short)((u + 0x7FFFu + ((u >> 16) & 1u)) >> 16);
}

// ---- integer wave-wide sum (lane movement validated R8-R17) ----
template<int CTRL>
__device__ __forceinline__ int dpp_addi(int x){
  int y = __builtin_amdgcn_mov_dpp(x, CTRL, 0xF, 0xF, true);
  return x + y;
}
__device__ __forceinline__ int iwaveSum(int x){
  x = dpp_addi<0x121>(x);
  x = dpp_addi<0x122>(x);
  x = dpp_addi<0x124>(x);
  x = dpp_addi<0x128>(x);
  {
    uint2v r = __builtin_amdgcn_permlane16_swap((unsigned)x, (unsigned)x, false, false);
    x = (int)r[0] + (int)r[1];
  }
  {
    uint2v r = __builtin_amdgcn_permlane32_swap((unsigned)x, (unsigned)x, false, false);
    x = (int)r[0] + (int)r[1];
  }
  return x;
}
// sum of v[j] for j < lim (v has 128 entries); every lane returns the total.
__device__ __forceinline__ int maskedSum128(const int* __restrict__ v,
                                            int lim, int lane){
  const int a = v[2 * lane];
  const int b = v[2 * lane + 1];
  int s = ((2 * lane) < lim ? a : 0) + ((2 * lane + 1) < lim ? b : 0);
  return iwaveSum(s);
}

// ---- gather valid rows + f32->bf16 convert. Block = one source row.
// R18: (r==0)/(w==0) blocks also persist rowoff[i]/coloff[c] to ws so sink
// reads them as scalar loads (removes its 2 in-wave scans). ----
__global__ __launch_bounds__(256) void gather_cvt_kernel(
    const float* __restrict__ imgs, const float* __restrict__ caps,
    const int* __restrict__ il, const int* __restrict__ cl,
    unsigned short* __restrict__ Ab, unsigned short* __restrict__ Bb,
    int* __restrict__ rowoff, int* __restrict__ coloff){
  const int b = blockIdx.x;
  const int t = threadIdx.x;
  const int lane = t & 63;
  if (b < BI * RR){
    const int i = b / RR, r = b % RR;
    if (r >= il[i]) return;                       // block-uniform
    const int ro = maskedSum128(il, i, lane);     // rowoff[i], wave-computed
    if (r == 0 && t == 0) rowoff[i] = ro;         // persist for sink
    const float4 v = *(const float4*)(imgs + (size_t)b * DD + t * 4);
    ushort4 o = make_ushort4(f2bf(v.x), f2bf(v.y), f2bf(v.z), f2bf(v.w));
    *(ushort4*)(Ab + (size_t)(ro + r) * DD + t * 4) = o;
  } else {
    const int bb = b - BI * RR;
    const int c = bb / WW, w = bb % WW;
    if (w >= cl[c]) return;
    const int co = maskedSum128(cl, c, lane);     // coloff[c]
    if (w == 0 && t == 0) coloff[c] = co;
    const float4 v = *(const float4*)(caps + (size_t)bb * DD + t * 4);
    ushort4 o = make_ushort4(f2bf(v.x), f2bf(v.y), f2bf(v.z), f2bf(v.w));
    *(ushort4*)(Bb + (size_t)(co + w) * DD + t * 4) = o;
  }
}

// ---- 128x128 GEMM, BK=32, triple-buffered LDS, depth-2 prefetch, compact
// grid (validated R11-R17). R18: NORMAL C stores (NT removed) so fg stays
// L3-resident for sink's reads — isolating the NT lever R11 bundled. ----
__global__ __launch_bounds__(256) void gemm_kernel(
    const unsigned short* __restrict__ A, const unsigned short* __restrict__ B,
    const int* __restrict__ il, const int* __restrict__ cl,
    float* __restrict__ C){
  __shared__ __align__(16) unsigned char LDS[49152];
  const int tid = threadIdx.x;
  const int lane = tid & 63, wv = tid >> 6;
  const int Mp = __builtin_amdgcn_readfirstlane(maskedSum128(il, BI, lane));
  const int Np = __builtin_amdgcn_readfirstlane(maskedSum128(cl, BT, lane));
  const int nnb = (Np + 127) >> 7;
  const int nact = ((Mp + 127) >> 7) * nnb;
  const int bx = blockIdx.x;
  if (bx >= nact) return;                         // compact early-exit
  const int mb = bx / nnb, nb = bx - mb * nnb;
  const int m0 = mb * 128, n0 = nb * 128;

  const int l15 = lane & 15, lhi = lane >> 4;
  const int wr = wv >> 1, wc = wv & 1;            // 2x2 wave grid, 64x64/wave

  // staging sources: 4 units/thread/chunk (u = j*256+tid; A: u<512, B: u>=512)
  const unsigned short* sp[4];
  #pragma unroll
  for (int j = 0; j < 4; j++){
    const int u = j * 256 + tid;
    const int v = u & 511;
    const int sup = v >> 3, slot = v & 7;
    const int sub = slot ^ (sup & 7);             // inverse of store swizzle
    const int row = sup * 2 + (sub >> 2);
    const int kg  = sub & 3;
    sp[j] = ((u < 512) ? (A + (size_t)(m0 + row) * DD)
                       : (B + (size_t)(n0 + row) * DD)) + kg * 8;
  }

  float4v acc[4][4];
  #pragma unroll
  for (int a1 = 0; a1 < 4; a1++)
    #pragma unroll
    for (int b1 = 0; b1 < 4; b1++)
      acc[a1][b1] = (float4v){0.f, 0.f, 0.f, 0.f};

#define STAGE(BUF, CH) { \
    _Pragma("unroll") \
    for (int j = 0; j < 4; j++) \
      __builtin_amdgcn_global_load_lds( \
          (const __attribute__((address_space(1))) void*)(sp[j] + (CH) * 32), \
          (__attribute__((address_space(3))) void*)(LDS + (BUF) * 16384 + (j * 256 + tid) * 16), \
          16, 0, 0); }

#define LUNIT(row) (((row) >> 1) * 8 + (((((row) & 1) << 2) + lhi) ^ (((row) >> 1) & 7)))

#define COMPUTE(BUF) { \
    short8v af[4], bf[4]; \
    _Pragma("unroll") \
    for (int tr = 0; tr < 4; tr++){ \
      const int row = wr * 64 + tr * 16 + l15; \
      af[tr] = *(const short8v*)(LDS + (BUF) * 16384 + LUNIT(row) * 16); \
    } \
    _Pragma("unroll") \
    for (int tw = 0; tw < 4; tw++){ \
      const int row = wc * 64 + tw * 16 + l15; \
      bf[tw] = *(const short8v*)(LDS + (BUF) * 16384 + 8192 + LUNIT(row) * 16); \
    } \
    _Pragma("unroll") \
    for (int tr = 0; tr < 4; tr++) \
      _Pragma("unroll") \
      for (int tw = 0; tw < 4; tw++) \
        acc[tr][tw] = __builtin_amdgcn_mfma_f32_16x16x32_bf16( \
            af[tr], bf[tw], acc[tr][tw], 0, 0, 0); }

#define WAIT8  asm volatile("s_waitcnt vmcnt(8)" ::: "memory")
#define WAIT4  asm volatile("s_waitcnt vmcnt(4)" ::: "memory")
#define WAIT0  asm volatile("s_waitcnt vmcnt(0)" ::: "memory")
#define BAR    __builtin_amdgcn_s_barrier()

  STAGE(0, 0);                    // prologue: chunks 0,1 in flight
  STAGE(1, 1);
  #pragma unroll 1
  for (int k = 0; k < 10; k++){   // chunks 3k, 3k+1, 3k+2 in bufs 0,1,2
    const int c = 3 * k;
    STAGE(2, c + 2); WAIT8; BAR; COMPUTE(0); BAR;   // compute chunk c
    STAGE(0, c + 3); WAIT8; BAR; COMPUTE(1); BAR;   // chunk c+1
    STAGE(1, c + 4); WAIT8; BAR; COMPUTE(2); BAR;   // chunk c+2
  }
  WAIT4; BAR; COMPUTE(0); BAR;    // chunk 30 (staged at k=9 step B)
  WAIT0; BAR; COMPUTE(1);         // chunk 31 (staged at k=9 step C)

#undef STAGE
#undef LUNIT
#undef COMPUTE
#undef WAIT8
#undef WAIT4
#undef WAIT0
#undef BAR

  // C/D layout: col = lane&15, row = lhi*4 + j (m89/m91, validated R1-R17).
  // Normal stores: fg lands in L2/L3 so sink reads it at cache latency.
  #pragma unroll
  for (int tr = 0; tr < 4; tr++)
    #pragma unroll
    for (int tw = 0; tw < 4; tw++)
      #pragma unroll
      for (int j = 0; j < 4; j++){
        int m = m0 + wr * 64 + tr * 16 + lhi * 4 + j;
        int n = n0 + wc * 64 + tw * 16 + l15;
        C[(size_t)m * NN + n] = acc[tr][tw][j];
      }
}

// ---- float reduction helpers (validated R1-R17) ----
template<int CTRL>
__device__ __forceinline__ float dpp_add(float x){
  int y = __builtin_amdgcn_mov_dpp(__float_as_int(x), CTRL, 0xF, 0xF, true);
  return x + __int_as_float(y);
}
__device__ __forceinline__ float q16sum(float x){
  x = dpp_add<0x121>(x);   // row_ror:1
  x = dpp_add<0x122>(x);   // row_ror:2
  x = dpp_add<0x124>(x);   // row_ror:4
  x = dpp_add<0x128>(x);   // row_ror:8
  return x;
}
__device__ __forceinline__ float pl16comb(float x){
  unsigned xi = __float_as_uint(x);
  uint2v r = __builtin_amdgcn_permlane16_swap(xi, xi, false, false);
  return __uint_as_float(r[0]) + __uint_as_float(r[1]);
}
__device__ __forceinline__ float pl32comb(float x){
  unsigned xi = __float_as_uint(x);
  uint2v r = __builtin_amdgcn_permlane32_swap(xi, xi, false, false);
  return __uint_as_float(r[0]) + __uint_as_float(r[1]);
}

// ---- Sinkhorn: EXACT R11 body (56-64 VGPR, no spill, ~73% VALUBusy — the
// proven-stable optimum across R12-R15 alternatives). ONE pair per wave;
// quarter q owns rows 9q..9q+8; lane (q,t) holds cols t,t+16,t+32,t+48.
// R18: rowoff/coloff read from ws (written by gather) — no in-wave scans. ----
__global__ __launch_bounds__(256) void sink_kernel(
    const float* __restrict__ fg, const int* __restrict__ il,
    const int* __restrict__ cl, const int* __restrict__ rowoff,
    const int* __restrict__ coloff, float* __restrict__ out){
  const int lane = threadIdx.x & 63;
  const int gw = blockIdx.x * 4 + (threadIdx.x >> 6);   // 16384 waves
  const int i = gw >> 7, c = gw & 127;
  const int q = lane >> 4, t = lane & 15;

  const int ilen = __builtin_amdgcn_readfirstlane(il[i]);
  const int clen = __builtin_amdgcn_readfirstlane(cl[c]);
  const int ro   = __builtin_amdgcn_readfirstlane(rowoff[i]);
  const int co   = __builtin_amdgcn_readfirstlane(coloff[c]);
  const float* base = fg + (size_t)ro * NN + co;        // wave-uniform (saddr)
  const float inv_il = __fdividef(1.0f, (float)ilen);
  const float inv_cl = __fdividef(1.0f, (float)clen);
  const bool v0 = (t      < clen);
  const bool v1 = (t + 16 < clen);
  const bool v2 = (t + 32 < clen);
  const bool v3 = (t + 48 < clen);
  const int r0 = 9 * q;                                 // this quarter's rows
  const int off0 = r0 * NN + t;                         // 32-bit elem offset

  float p0[9], p1[9], p2[9], p3[9];
  float ts = 0.f;
  #pragma unroll
  for (int k = 0; k < 9; k++){
    const bool rv = (r0 + k) < ilen;
    const float a0 = base[off0 + k * NN];
    const float a1 = base[off0 + k * NN + 16];
    const float a2 = base[off0 + k * NN + 32];
    const float a3 = base[off0 + k * NN + 48];
    p0[k] = (rv && v0) ? exp2f(fmaf(a0, L2E20, -L2E20)) : 0.f;
    p1[k] = (rv && v1) ? exp2f(fmaf(a1, L2E20, -L2E20)) : 0.f;
    p2[k] = (rv && v2) ? exp2f(fmaf(a2, L2E20, -L2E20)) : 0.f;
    p3[k] = (rv && v3) ? exp2f(fmaf(a3, L2E20, -L2E20)) : 0.f;
    ts += (p0[k] + p1[k]) + (p2[k] + p3[k]);
  }
  ts = q16sum(ts);
  ts = pl16comb(ts);
  ts = pl32comb(ts);
  const float sc = __fdividef(1.0f, ts + SEPS);         // P /= (sum + EPS)
  #pragma unroll
  for (int k = 0; k < 9; k++){
    p0[k] *= sc; p1[k] *= sc; p2[k] *= sc; p3[k] *= sc;
  }

  for (int it = 0; it < 3; it++){
    #pragma unroll
    for (int k = 0; k < 9; k++){                        // u = rowsum + EPS
      float u = (p0[k] + p1[k]) + (p2[k] + p3[k]);
      u = q16sum(u);
      const float rs = __fdividef(inv_il, u + SEPS);
      p0[k] *= rs; p1[k] *= rs; p2[k] *= rs; p3[k] *= rs;
    }
    float s0 = 0.f, s1 = 0.f, s2 = 0.f, s3 = 0.f;       // colsums (in-lane)
    #pragma unroll
    for (int k = 0; k < 9; k++){
      s0 += p0[k]; s1 += p1[k]; s2 += p2[k]; s3 += p3[k];
    }
    s0 = pl16comb(s0); s0 = pl32comb(s0);
    s1 = pl16comb(s1); s1 = pl32comb(s1);
    s2 = pl16comb(s2); s2 = pl32comb(s2);
    s3 = pl16comb(s3); s3 = pl32comb(s3);
    const float cs0 = __fdividef(inv_cl, s0 + SEPS);
    const float cs1 = __fdividef(inv_cl, s1 + SEPS);
    const float cs2 = __fdividef(inv_cl, s2 + SEPS);
    const float cs3 = __fdividef(inv_cl, s3 + SEPS);
    #pragma unroll
    for (int k = 0; k < 9; k++){
      p0[k] *= cs0; p1[k] *= cs1; p2[k] *= cs2; p3[k] *= cs3;
    }
  }

  float sim = 0.f;
  #pragma unroll
  for (int k = 0; k < 9; k++){                          // reload f (L3-hot)
    sim = fmaf(base[off0 + k * NN],      p0[k], sim);
    sim = fmaf(base[off0 + k * NN + 16], p1[k], sim);
    sim = fmaf(base[off0 + k * NN + 32], p2[k], sim);
    sim = fmaf(base[off0 + k * NN + 48], p3[k], sim);
  }
  sim = q16sum(sim);
  sim = pl16comb(sim);
  sim = pl32comb(sim);
  if (lane == 0) out[i * BT + c] = sim;
}

extern "C" void kernel_launch(void* const* d_in, const int* in_sizes, int n_in,
                              void* d_out, int out_size, void* d_ws, size_t ws_size,
                              hipStream_t stream){
  const float* imgs = (const float*)d_in[0];
  const float* caps = (const float*)d_in[1];
  const int* il = (const int*)d_in[2];
  const int* cl = (const int*)d_in[3];
  float* out = (float*)d_out;

  unsigned short* Ab = (unsigned short*)d_ws;               // [4608][1024] bf16
  unsigned short* Bb = Ab + (size_t)BI * RR * DD;           // [6400][1024] bf16
  float* fg = (float*)(Bb + (size_t)BT * WW * DD);          // [4608][6400] f32
  int* rowoff = (int*)(fg + (size_t)BI * RR * NN);          // [128]
  int* coloff = rowoff + 128;                               // [128]

  gather_cvt_kernel<<<BI * RR + BT * WW, 256, 0, stream>>>(
      imgs, caps, il, cl, Ab, Bb, rowoff, coloff);
  gemm_kernel<<<36 * 50, 256, 0, stream>>>(Ab, Bb, il, cl, fg);
  sink_kernel<<<(BI * BT) / 4, 256, 0, stream>>>(fg, il, cl, rowoff, coloff, out);
}